// Round 7
// baseline (213.112 us; speedup 1.0000x reference)
//
#include <hip/hip_runtime.h>
#include <hip/hip_bf16.h>
#include <stdint.h>

// Problem constants (ManualMHA): B=2, T=2048, D=1024, H=16, DK=64
#define B_   2
#define T_   2048
#define D_   1024
#define H_   16
#define DK_  64
#define KL2_ 0.18033688f   // SCALE * log2(e) = 0.125 * 1.4426950408889634

typedef __attribute__((ext_vector_type(8))) short   short8;   // 8 x bf16 (4 VGPRs)
typedef __attribute__((ext_vector_type(4))) float   floatx4;  // MFMA C/D
typedef unsigned short ushort_t;
typedef unsigned int   uint_t;

// ---------------------------------------------------------------- helpers
__device__ __forceinline__ ushort_t f32_to_bf16(float f) {
    union { float f; unsigned int u; } v; v.f = f;
    unsigned int r = v.u + 0x7fffu + ((v.u >> 16) & 1u);   // RNE
    return (ushort_t)(r >> 16);
}

// pack two fp32 -> (bf16(hi)<<16)|bf16(lo) with +0x8000 round bias, 3 VALU ops
__device__ __forceinline__ uint_t pk_bf16(float lo, float hi) {
    uint_t ulo = __builtin_bit_cast(uint_t, lo) + 0x8000u;
    uint_t uhi = __builtin_bit_cast(uint_t, hi) + 0x8000u;
    return __builtin_amdgcn_perm(uhi, ulo, 0x07060302);  // bytes: lo[2],lo[3],hi[2],hi[3]
}

__device__ __forceinline__ void async_copy16(const ushort_t* g, ushort_t* l) {
    typedef const unsigned int __attribute__((address_space(1)))* gp_t;
    typedef       unsigned int __attribute__((address_space(3)))* lp_t;
    __builtin_amdgcn_global_load_lds((gp_t)(uintptr_t)g, (lp_t)(uintptr_t)l, 16, 0, 0);
}

// ---------------------------------------------------------------- fused fp32 -> bf16 cast
__global__ __launch_bounds__(256) void cast_all_kernel(
    const float* __restrict__ q, const float* __restrict__ k, const float* __restrict__ v,
    const float* __restrict__ wq, const float* __restrict__ wk,
    const float* __restrict__ wv, const float* __restrict__ wo,
    ushort_t* __restrict__ oq, ushort_t* __restrict__ ok, ushort_t* __restrict__ ov,
    ushort_t* __restrict__ owq, ushort_t* __restrict__ owk,
    ushort_t* __restrict__ owv, ushort_t* __restrict__ owo)
{
    const int NTD4 = (B_ * T_ * D_) / 4;   // 1048576
    const int NW4  = (D_ * D_) / 4;        // 262144
    int i = blockIdx.x * 256 + threadIdx.x;
    const float* s; ushort_t* d; int off;
    if (i < NTD4)              { s = q; d = oq; off = i; }
    else if (i < 2 * NTD4)     { s = k; d = ok; off = i - NTD4; }
    else if (i < 3 * NTD4)     { s = v; d = ov; off = i - 2 * NTD4; }
    else {
        int w = i - 3 * NTD4;
        int seg = w / NW4;  off = w - seg * NW4;
        s = (seg == 0) ? wq : (seg == 1) ? wk : (seg == 2) ? wv : wo;
        d = (seg == 0) ? owq : (seg == 1) ? owk : (seg == 2) ? owv : owo;
    }
    float4 x = ((const float4*)s)[off];
    ushort4 o;
    o.x = f32_to_bf16(x.x); o.y = f32_to_bf16(x.y);
    o.z = f32_to_bf16(x.z); o.w = f32_to_bf16(x.w);
    ((ushort4*)d)[off] = o;
}

// ---------------------------------------------------------------- legacy GEMM path (gemm_o only)
#define BM 128
#define BK 32

template<int MODE, int NI>
__device__ __forceinline__ void gemm_bt_device(
    const ushort_t* __restrict__ A, const ushort_t* __restrict__ W,
    const float* __restrict__ bias, void* __restrict__ outp,
    int m0, int n0, ushort_t* sm, float oscale)
{
    const int tid  = threadIdx.x;
    const int lane = tid & 63;
    const int wv   = tid >> 6;
    const int wm   = (wv >> 1) * 64;
    const int wn   = (wv & 1) * (NI * 16);
    const int cl   = lane & 15;
    const int qd   = lane >> 4;
    const int sw4  = (cl >> 1) & 3;      // fragment-read chunk swizzle

    floatx4 acc[4][NI];
    const floatx4 z4 = {0.f, 0.f, 0.f, 0.f};
    #pragma unroll
    for (int mi = 0; mi < 4; ++mi)
        #pragma unroll
        for (int ni = 0; ni < NI; ++ni) acc[mi][ni] = z4;

    const int r0 = tid >> 2;
    const int cg = (tid & 3) ^ ((r0 >> 1) & 3);
    const ushort_t* Ag0 = A + (size_t)(m0 + r0) * 1024 + cg * 8;
    const ushort_t* Ag1 = A + (size_t)(m0 + 64 + r0) * 1024 + cg * 8;
    const ushort_t* Wg0 = W + (size_t)(n0 + r0) * 1024 + cg * 8;
    const ushort_t* Wg1 = W + (size_t)(n0 + 64 + r0) * 1024 + cg * 8;
    ushort_t* As0 = sm + tid * 8;
    ushort_t* As1 = sm + 2048 + tid * 8;
    ushort_t* Bs0 = sm + 4096 + tid * 8;
    ushort_t* Bs1 = sm + 6144 + tid * 8;

    for (int k0 = 0; k0 < 1024; k0 += BK) {
        async_copy16(Ag0 + k0, As0);
        async_copy16(Ag1 + k0, As1);
        async_copy16(Wg0 + k0, Bs0);
        if (NI == 4) async_copy16(Wg1 + k0, Bs1);
        __syncthreads();

        short8 af[4], bfr[NI];
        #pragma unroll
        for (int mi = 0; mi < 4; ++mi)
            af[mi] = *(const short8*)(sm + (wm + mi * 16 + cl) * 32 + (qd ^ sw4) * 8);
        #pragma unroll
        for (int ni = 0; ni < NI; ++ni)
            bfr[ni] = *(const short8*)(sm + 4096 + (wn + ni * 16 + cl) * 32 + (qd ^ sw4) * 8);

        #pragma unroll
        for (int mi = 0; mi < 4; ++mi)
            #pragma unroll
            for (int ni = 0; ni < NI; ++ni)
                acc[mi][ni] = __builtin_amdgcn_mfma_f32_16x16x32_bf16(
                    af[mi], bfr[ni], acc[mi][ni], 0, 0, 0);
        __syncthreads();
    }

    #pragma unroll
    for (int mi = 0; mi < 4; ++mi) {
        #pragma unroll
        for (int ni = 0; ni < NI; ++ni) {
            const int n = n0 + wn + ni * 16 + cl;
            const float bn = bias[n];
            if (MODE == 0) {
                float* out = (float*)outp;
                #pragma unroll
                for (int r = 0; r < 4; ++r) {
                    const int m = m0 + wm + mi * 16 + qd * 4 + r;
                    out[(size_t)m * D_ + n] = acc[mi][ni][r] + bn;
                }
            } else if (MODE == 1) {
                ushort_t* out = (ushort_t*)outp;
                const int h = n >> 6, dk = n & 63;
                #pragma unroll
                for (int r = 0; r < 4; ++r) {
                    const int m = m0 + wm + mi * 16 + qd * 4 + r;
                    const int b = m >> 11, t = m & (T_ - 1);
                    out[(((size_t)(b * H_ + h)) * T_ + t) * DK_ + dk] =
                        f32_to_bf16((acc[mi][ni][r] + bn) * oscale);
                }
            } else {
                ushort_t* out = (ushort_t*)outp;
                const int h = n >> 6, dk = n & 63;
                const int mb = m0 + wm + mi * 16 + qd * 4;
                const int b = mb >> 11, t0 = mb & (T_ - 1);
                const int tsw = (t0 & ~60) | ((t0 & 48) >> 2) | ((t0 & 12) << 2);
                ushort4 o;
                o.x = f32_to_bf16(acc[mi][ni][0] + bn);
                o.y = f32_to_bf16(acc[mi][ni][1] + bn);
                o.z = f32_to_bf16(acc[mi][ni][2] + bn);
                o.w = f32_to_bf16(acc[mi][ni][3] + bn);
                *(ushort4*)(out + (((size_t)(b * H_ + h)) * DK_ + dk) * T_ + tsw) = o;
            }
        }
    }
}

// gemm_o: BN=64 (NI=2) -> 512 blocks = 2 blocks/CU co-resident.
__global__ __launch_bounds__(256) void gemm_o_kernel(
    const ushort_t* __restrict__ A, const ushort_t* __restrict__ W,
    const float* __restrict__ bias, float* __restrict__ out)
{
    __shared__ __align__(16) ushort_t sm[8192];
    gemm_bt_device<0, 2>(A, W, bias, out, blockIdx.x * BM, blockIdx.y * 64, sm, 1.0f);
}

// ---------------------------------------------------------------- R13: fused QKV GEMM, 256^2 8-phase
// (verified R5: passed, absmax 0.0078)
__device__ __forceinline__ void ldA4(short8 (&af)[4][2], const ushort_t* base, int coff) {
    #pragma unroll
    for (int mi = 0; mi < 4; ++mi) {
        af[mi][0] = *(const short8*)(base + mi * 1024 + coff);
        af[mi][1] = *(const short8*)(base + mi * 1024 + (coff ^ 32));
    }
}
__device__ __forceinline__ void ldB2(short8 (&bf)[2][2], const ushort_t* base, int coff) {
    #pragma unroll
    for (int ni = 0; ni < 2; ++ni) {
        bf[ni][0] = *(const short8*)(base + ni * 1024 + coff);
        bf[ni][1] = *(const short8*)(base + ni * 1024 + (coff ^ 32));
    }
}

template<int MQ, int NQ>
__device__ __forceinline__ void quad16(floatx4 (&acc)[8][4],
                                       const short8 (&af)[4][2],
                                       const short8 (&bf)[2][2])
{
    __builtin_amdgcn_s_setprio(1);
    #pragma unroll
    for (int mi = 0; mi < 4; ++mi)
        #pragma unroll
        for (int ni = 0; ni < 2; ++ni) {
            acc[MQ * 4 + mi][NQ * 2 + ni] = __builtin_amdgcn_mfma_f32_16x16x32_bf16(
                af[mi][0], bf[ni][0], acc[MQ * 4 + mi][NQ * 2 + ni], 0, 0, 0);
            acc[MQ * 4 + mi][NQ * 2 + ni] = __builtin_amdgcn_mfma_f32_16x16x32_bf16(
                af[mi][1], bf[ni][1], acc[MQ * 4 + mi][NQ * 2 + ni], 0, 0, 0);
        }
    __builtin_amdgcn_s_setprio(0);
}

__global__ void __launch_bounds__(512, 2) gemm_qkv8_kernel(
    const ushort_t* __restrict__ Xq, const ushort_t* __restrict__ Xk, const ushort_t* __restrict__ Xv,
    const ushort_t* __restrict__ Wqw, const ushort_t* __restrict__ Wkw, const ushort_t* __restrict__ Wvw,
    const float* __restrict__ bq, const float* __restrict__ bk, const float* __restrict__ bv,
    ushort_t* __restrict__ Qo, ushort_t* __restrict__ Ko, ushort_t* __restrict__ Vto)
{
    extern __shared__ __align__(16) ushort_t sm[];   // 131072 B

    const int bid    = blockIdx.x;
    const int gid    = (bid & 7) * 24 + (bid >> 3);
    const int m_tile = gid / 12;
    const int n_tile = gid - m_tile * 12;
    const int m0     = m_tile * 256;
    const int seg    = n_tile >> 2;          // 0:Q 1:K 2:V
    const int n0     = (n_tile & 3) * 256;   // within segment

    const ushort_t* A    = (seg == 0) ? Xq  : (seg == 1) ? Xk  : Xv;
    const ushort_t* W    = (seg == 0) ? Wqw : (seg == 1) ? Wkw : Wvw;
    const float*    bias = (seg == 0) ? bq  : (seg == 1) ? bk  : bv;

    const int tid  = threadIdx.x;
    const int lane = tid & 63;
    const int wv   = tid >> 6;        // 0..7
    const int wm   = wv >> 2;         // 0..1  (M half: 128 rows)
    const int wn   = wv & 3;          // 0..3  (64-col group)
    const int cl   = lane & 15;
    const int qd   = lane >> 4;
    const int swz  = cl & 7;
    const int coff = (qd ^ swz) * 8;  // chunk0 byte-offset (shorts); chunk1 = ^32

    const int r0 = tid >> 3;
    const int c0 = (tid & 7) ^ (r0 & 7);
    const ushort_t* gA = A + (size_t)(m0 + r0) * 1024 + c0 * 8;
    const ushort_t* gB = W + (size_t)(n0 + r0) * 1024 + c0 * 8;
    ushort_t* lbase = sm + tid * 8;

    auto stage = [&](int t, int op, int h) {
        if (t >= 16) return;
        const ushort_t* g = (op ? gB : gA) + (size_t)h * 131072 + (size_t)t * 64;
        ushort_t* l = lbase + (size_t)((t & 1) * 4 + op * 2 + h) * 8192;
        async_copy16(g, l);
        async_copy16(g + 65536, l + 4096);   // row r0+64
    };

    const ushort_t* A0 = sm + (0 * 4 + 0 * 2 + wm) * 8192 + cl * 64;
    const ushort_t* A1 = A0 + 4 * 8192;
    const ushort_t* B0 = sm + (0 * 4 + 1 * 2 + (wn >> 1)) * 8192 + (wn & 1) * 4096 + cl * 64;
    const ushort_t* B1 = B0 + 4 * 8192;

    floatx4 acc[8][4];
    const floatx4 z4 = {0.f, 0.f, 0.f, 0.f};
    #pragma unroll
    for (int i = 0; i < 8; ++i)
        #pragma unroll
        for (int j = 0; j < 4; ++j) acc[i][j] = z4;

    stage(0, 0, 0); stage(0, 0, 1); stage(0, 1, 0); stage(0, 1, 1);
    stage(1, 1, 0); stage(1, 1, 1);
    asm volatile("s_waitcnt vmcnt(4)" ::: "memory");
    __builtin_amdgcn_s_barrier();

    short8 af[4][2], bf0[2][2], bf1[2][2];

    #pragma unroll 1
    for (int it = 0; it < 7; ++it) {
        const int u = 2 * it, v = u + 1;
        // ---------------- tile u (dbuf 0) ----------------
        ldA4(af, A0, coff); ldB2(bf0, B0, coff);
        stage(v, 0, 0);
        __builtin_amdgcn_s_barrier();
        quad16<0, 0>(acc, af, bf0);
        __builtin_amdgcn_s_barrier();
        ldB2(bf1, B0 + 2048, coff);
        stage(v, 0, 1);
        __builtin_amdgcn_s_barrier();
        quad16<0, 1>(acc, af, bf1);
        __builtin_amdgcn_s_barrier();
        ldA4(af, A0 + 4096, coff);
        stage(u + 2, 1, 0);
        __builtin_amdgcn_s_barrier();
        quad16<1, 1>(acc, af, bf1);
        __builtin_amdgcn_s_barrier();
        stage(u + 2, 1, 1);
        asm volatile("s_waitcnt vmcnt(4)" ::: "memory");
        __builtin_amdgcn_s_barrier();
        quad16<1, 0>(acc, af, bf0);
        __builtin_amdgcn_s_barrier();
        // ---------------- tile v (dbuf 1) ----------------
        ldA4(af, A1, coff); ldB2(bf0, B1, coff);
        stage(u + 2, 0, 0);
        __builtin_amdgcn_s_barrier();
        quad16<0, 0>(acc, af, bf0);
        __builtin_amdgcn_s_barrier();
        ldB2(bf1, B1 + 2048, coff);
        stage(u + 2, 0, 1);
        __builtin_amdgcn_s_barrier();
        quad16<0, 1>(acc, af, bf1);
        __builtin_amdgcn_s_barrier();
        ldA4(af, A1 + 4096, coff);
        stage(v + 2, 1, 0);
        __builtin_amdgcn_s_barrier();
        quad16<1, 1>(acc, af, bf1);
        __builtin_amdgcn_s_barrier();
        stage(v + 2, 1, 1);
        asm volatile("s_waitcnt vmcnt(4)" ::: "memory");
        __builtin_amdgcn_s_barrier();
        quad16<1, 0>(acc, af, bf0);
        __builtin_amdgcn_s_barrier();
    }

    // peeled final iteration (tiles 14, 15): drains vmcnt(0) before tile 15
    ldA4(af, A0, coff); ldB2(bf0, B0, coff);
    stage(15, 0, 0);
    __builtin_amdgcn_s_barrier();
    quad16<0, 0>(acc, af, bf0);
    __builtin_amdgcn_s_barrier();
    ldB2(bf1, B0 + 2048, coff);
    stage(15, 0, 1);
    __builtin_amdgcn_s_barrier();
    quad16<0, 1>(acc, af, bf1);
    __builtin_amdgcn_s_barrier();
    ldA4(af, A0 + 4096, coff);
    __builtin_amdgcn_s_barrier();
    quad16<1, 1>(acc, af, bf1);
    __builtin_amdgcn_s_barrier();
    asm volatile("s_waitcnt vmcnt(0)" ::: "memory");
    __builtin_amdgcn_s_barrier();
    quad16<1, 0>(acc, af, bf0);
    __builtin_amdgcn_s_barrier();
    ldA4(af, A1, coff); ldB2(bf0, B1, coff);
    __builtin_amdgcn_s_barrier();
    quad16<0, 0>(acc, af, bf0);
    __builtin_amdgcn_s_barrier();
    ldB2(bf1, B1 + 2048, coff);
    __builtin_amdgcn_s_barrier();
    quad16<0, 1>(acc, af, bf1);
    __builtin_amdgcn_s_barrier();
    ldA4(af, A1 + 4096, coff);
    __builtin_amdgcn_s_barrier();
    quad16<1, 1>(acc, af, bf1);
    __builtin_amdgcn_s_barrier();
    quad16<1, 0>(acc, af, bf0);

    // ---------------- epilogue ----------------
    float bn[4];
    #pragma unroll
    for (int nf = 0; nf < 4; ++nf)
        bn[nf] = bias[n0 + wn * 64 + nf * 16 + cl];

    if (seg < 2) {
        ushort_t* out = (seg == 0) ? Qo : Ko;
        const float oscale = (seg == 0) ? KL2_ : 1.0f;
        #pragma unroll
        for (int mf = 0; mf < 8; ++mf) {
            #pragma unroll
            for (int nf = 0; nf < 4; ++nf) {
                const int n = n0 + wn * 64 + nf * 16 + cl;
                const int h = n >> 6, dk = n & 63;
                #pragma unroll
                for (int r = 0; r < 4; ++r) {
                    const int m = m0 + wm * 128 + mf * 16 + qd * 4 + r;
                    const int b = m >> 11, t = m & (T_ - 1);
                    out[(((size_t)(b * H_ + h)) * T_ + t) * DK_ + dk] =
                        f32_to_bf16((acc[mf][nf][r] + bn[nf]) * oscale);
                }
            }
        }
    } else {
        #pragma unroll
        for (int mf = 0; mf < 8; ++mf) {
            #pragma unroll
            for (int nf = 0; nf < 4; ++nf) {
                const int n = n0 + wn * 64 + nf * 16 + cl;
                const int h = n >> 6, dk = n & 63;
                const int mb = m0 + wm * 128 + mf * 16 + qd * 4;
                const int b = mb >> 11, t0 = mb & (T_ - 1);
                const int tsw = (t0 & ~60) | ((t0 & 48) >> 2) | ((t0 & 12) << 2);
                ushort4 o;
                o.x = f32_to_bf16(acc[mf][nf][0] + bn[nf]);
                o.y = f32_to_bf16(acc[mf][nf][1] + bn[nf]);
                o.z = f32_to_bf16(acc[mf][nf][2] + bn[nf]);
                o.w = f32_to_bf16(acc[mf][nf][3] + bn[nf]);
                *(ushort4*)(Vto + (((size_t)(b * H_ + h)) * DK_ + dk) * T_ + tsw) = o;
            }
        }
    }
}

// ---------------------------------------------------------------- flash attention
// R14: __syncthreads -> {bar; stage; counted vmcnt(8/4/0); bar} (T3/T4).
// The old __syncthreads emitted s_waitcnt vmcnt(0) before s_barrier, draining
// the 2-step-ahead prefetch every group -- the pipeline never existed.
// Counted scheme (each stage_step = 4 copies, 2 steps/group = 8): entering
// group g, 8 copies in flight = stages s0,s0+1 (issued in g-1). Top barrier
// = all waves done reading bufs (s0+2)&3,(s0+3)&3. Issue this group's stages
// (8 newest), vmcnt(N=just-issued) drains the previous group's 8 (+ flush
// stores / Q reloads, which are older and drain too -- never protected).
// Second barrier publishes landing. Tail: g=15 -> vmcnt(4); g=16 -> vmcnt(0).
// T5 setprio around QK and PV MFMA clusters (m191: +4-7% attn).
__global__ __launch_bounds__(256, 2) void attn_kernel(
    const ushort_t* __restrict__ Q, const ushort_t* __restrict__ K,
    const ushort_t* __restrict__ Vs, ushort_t* __restrict__ O)
{
    __shared__ __align__(16) ushort_t sm[32768];  // 4 bufs x (K 4096 + V 4096)
    const int tid  = threadIdx.x;
    const int lane = tid & 63;
    const int wv   = tid >> 6;
    const int cl   = lane & 15;
    const int qd   = lane >> 4;
    const int swz  = cl & 7;
    const int h = blockIdx.x & (H_ - 1), b = blockIdx.x >> 4;
    const int p   = blockIdx.y;          // pair id 0..15
    const int btA = 31 - p;              // deep 64-row tile; tile B = p

    const ushort_t* Qh = Q  + ((size_t)(b * H_ + h) * T_) * DK_;
    const ushort_t* Kh = K  + ((size_t)(b * H_ + h) * T_) * DK_;
    const ushort_t* Vh = Vs + ((size_t)(b * H_ + h) * DK_) * T_;

    const int sr  = tid >> 3;
    const int sc  = tid & 7;
    const int scg = sc ^ (sr & 7);

    auto stage_step = [&](int s) {
        const int kbase = ((s <= btA) ? s : (s - btA - 1)) << 6;
        ushort_t* Kb = sm + (s & 3) * 8192;
        ushort_t* Vb = Kb + 4096;
        #pragma unroll
        for (int rr = 0; rr < 2; ++rr) {
            const int r = rr * 32 + sr;
            async_copy16(Kh + (size_t)(kbase + r) * DK_ + scg * 8, Kb + r * 64 + sc * 8);
            async_copy16(Vh + (size_t)r * T_ + kbase + scg * 8,    Vb + r * 64 + sc * 8);
        }
    };

    int qw = btA * 64 + wv * 16;         // wave's q-row base (current tile)
    short8 qf0 = *(const short8*)(Qh + (size_t)(qw + cl) * DK_ + qd * 8);
    short8 qf1 = *(const short8*)(Qh + (size_t)(qw + cl) * DK_ + 32 + qd * 8);

    stage_step(0);
    stage_step(1);

    const floatx4 z4 = {0.f, 0.f, 0.f, 0.f};
    floatx4 oaccT[4] = {z4, z4, z4, z4}; // O^T tiles: row = dk, col = q
    float l_ = 0.f;

    auto flush = [&](int q0w) {
        float l = l_;
        l += __shfl_xor(l, 16, 64);
        l += __shfl_xor(l, 32, 64);
        const float inv = 1.0f / l;
        ushort_t* Ob = O + ((size_t)(b * T_ + q0w + cl)) * D_ + h * DK_ + qd * 4;
        #pragma unroll
        for (int dt = 0; dt < 4; ++dt) {
            ushort4 o;
            o.x = f32_to_bf16(oaccT[dt][0] * inv);
            o.y = f32_to_bf16(oaccT[dt][1] * inv);
            o.z = f32_to_bf16(oaccT[dt][2] * inv);
            o.w = f32_to_bf16(oaccT[dt][3] * inv);
            *(ushort4*)(Ob + dt * 16) = o;
        }
    };

    auto compute_step = [&](int s) {
        const bool inA  = (s <= btA);
        const int kbase = (inA ? s : (s - btA - 1)) << 6;
        const bool diag = inA ? (s == btA) : (s == 32);
        ushort_t* cb = sm + (s & 3) * 8192;
        short8 kb[4][2];
        #pragma unroll
        for (int m = 0; m < 4; ++m)
            #pragma unroll
            for (int i = 0; i < 2; ++i)
                kb[m][i] = *(const short8*)(cb + (m * 16 + cl) * 64 + ((i * 4 + qd) ^ swz) * 8);
        floatx4 sacc[4] = {z4, z4, z4, z4};
        __builtin_amdgcn_s_setprio(1);
        #pragma unroll
        for (int i = 0; i < 2; ++i)
            #pragma unroll
            for (int m = 0; m < 4; ++m)
                sacc[m] = __builtin_amdgcn_mfma_f32_16x16x32_bf16(
                    kb[m][i], (i ? qf1 : qf0), sacc[m], 0, 0, 0);
        __builtin_amdgcn_s_setprio(0);
        const int qabs = qw + cl;
        float pr[4][4];
        if (diag) {
            #pragma unroll
            for (int c = 0; c < 4; ++c)
                #pragma unroll
                for (int r = 0; r < 4; ++r) {
                    const bool keep = (kbase + c * 16 + qd * 4 + r) <= qabs;
                    const float e = __builtin_amdgcn_exp2f(sacc[c][r]);
                    pr[c][r] = keep ? e : 0.f;
                    l_ += pr[c][r];
                }
        } else {
            #pragma unroll
            for (int c = 0; c < 4; ++c)
                #pragma unroll
                for (int r = 0; r < 4; ++r) {
                    pr[c][r] = __builtin_amdgcn_exp2f(sacc[c][r]);
                    l_ += pr[c][r];
                }
        }
        short8 va2[4][2];
        #pragma unroll
        for (int dt = 0; dt < 4; ++dt)
            #pragma unroll
            for (int h2 = 0; h2 < 2; ++h2)
                va2[dt][h2] = *(const short8*)(cb + 4096 + (dt * 16 + cl) * 64 +
                                               ((qd * 2 + h2) ^ swz) * 8);
        #pragma unroll
        for (int cp = 0; cp < 2; ++cp) {
            union { uint_t u[4]; short8 v; } pb;
            pb.u[0] = pk_bf16(pr[cp * 2][0],     pr[cp * 2][1]);
            pb.u[1] = pk_bf16(pr[cp * 2][2],     pr[cp * 2][3]);
            pb.u[2] = pk_bf16(pr[cp * 2 + 1][0], pr[cp * 2 + 1][1]);
            pb.u[3] = pk_bf16(pr[cp * 2 + 1][2], pr[cp * 2 + 1][3]);
            __builtin_amdgcn_s_setprio(1);
            #pragma unroll
            for (int dt = 0; dt < 4; ++dt)
                oaccT[dt] = __builtin_amdgcn_mfma_f32_16x16x32_bf16(
                    va2[dt][cp], pb.v, oaccT[dt], 0, 0, 0);
            __builtin_amdgcn_s_setprio(0);
        }
        if (s == btA) {
            flush(qw);
            #pragma unroll
            for (int dt = 0; dt < 4; ++dt) oaccT[dt] = z4;
            l_ = 0.f;
            qw = p * 64 + wv * 16;
            qf0 = *(const short8*)(Qh + (size_t)(qw + cl) * DK_ + qd * 8);
            qf1 = *(const short8*)(Qh + (size_t)(qw + cl) * DK_ + 32 + qd * 8);
        }
    };

    #pragma unroll 1
    for (int g = 0; g < 17; ++g) {
        const int s0 = g * 2;
        __builtin_amdgcn_s_barrier();            // bufs (s0+2)&3,(s0+3)&3 free
        if (s0 + 2 <= 32) stage_step(s0 + 2);
        if (s0 + 3 <= 32) stage_step(s0 + 3);
        if (s0 + 3 <= 32)      { asm volatile("s_waitcnt vmcnt(8)" ::: "memory"); }
        else if (s0 + 2 <= 32) { asm volatile("s_waitcnt vmcnt(4)" ::: "memory"); }
        else                   { asm volatile("s_waitcnt vmcnt(0)" ::: "memory"); }
        __builtin_amdgcn_s_barrier();            // bufs s0, s0+1 landed everywhere
        compute_step(s0);
        if (s0 + 1 <= 32) compute_step(s0 + 1);
    }
    flush(qw);                           // tile B
}

// ---------------------------------------------------------------- launch
extern "C" void kernel_launch(void* const* d_in, const int* in_sizes, int n_in,
                              void* d_out, int out_size, void* d_ws, size_t ws_size,
                              hipStream_t stream)
{
    const float* q_in = (const float*)d_in[0];
    const float* k_in = (const float*)d_in[1];
    const float* v_in = (const float*)d_in[2];
    const float* Wq   = (const float*)d_in[3];
    const float* bq   = (const float*)d_in[4];
    const float* Wk   = (const float*)d_in[5];
    const float* bk   = (const float*)d_in[6];
    const float* Wv   = (const float*)d_in[7];
    const float* bv   = (const float*)d_in[8];
    const float* Wo   = (const float*)d_in[9];
    const float* bo   = (const float*)d_in[10];
    float* out = (float*)d_out;

    const size_t NTD = (size_t)B_ * T_ * D_;  // 4,194,304
    const size_t NW  = (size_t)D_ * D_;       // 1,048,576
    ushort_t* ws  = (ushort_t*)d_ws;
    ushort_t* Xq  = ws;
    ushort_t* Xk  = Xq + NTD;
    ushort_t* Xv  = Xk + NTD;
    ushort_t* Wqb = Xv + NTD;
    ushort_t* Wkb = Wqb + NW;
    ushort_t* Wvb = Wkb + NW;
    ushort_t* Wob = Wvb + NW;
    ushort_t* Qd  = Wob + NW;
    ushort_t* Kd  = Qd + NTD;
    ushort_t* Vtd = Kd + NTD;
    ushort_t* Od  = Vtd + NTD;

    const int total4 = (int)((3 * NTD + 4 * NW) / 4);   // 4,194,304
    cast_all_kernel<<<dim3(total4 / 256), dim3(256), 0, stream>>>(
        q_in, k_in, v_in, Wq, Wk, Wv, Wo,
        Xq, Xk, Xv, Wqb, Wkb, Wvb, Wob);

    static bool s_attr = false;
    if (!s_attr) {
        (void)hipFuncSetAttribute((const void*)gemm_qkv8_kernel,
                                  hipFuncAttributeMaxDynamicSharedMemorySize, 131072);
        s_attr = true;
    }
    gemm_qkv8_kernel<<<dim3(192), dim3(512), 131072, stream>>>(
        Xq, Xk, Xv, Wqb, Wkb, Wvb, bq, bk, bv, Qd, Kd, Vtd);

    attn_kernel<<<dim3(32, 16), dim3(256), 0, stream>>>(Qd, Kd, Vtd, Od);

    gemm_o_kernel<<<dim3(32, 16), dim3(256), 0, stream>>>(Od, Wob, bo, out);
}

// Round 9
// 210.156 us; speedup vs baseline: 1.0141x; 1.0141x over previous
//
#include <hip/hip_runtime.h>
#include <hip/hip_bf16.h>
#include <stdint.h>

// Problem constants (ManualMHA): B=2, T=2048, D=1024, H=16, DK=64
#define B_   2
#define T_   2048
#define D_   1024
#define H_   16
#define DK_  64
#define KL2_ 0.18033688f   // SCALE * log2(e) = 0.125 * 1.4426950408889634

typedef __attribute__((ext_vector_type(8))) short   short8;   // 8 x bf16 (4 VGPRs)
typedef __attribute__((ext_vector_type(4))) float   floatx4;  // MFMA C/D
typedef unsigned short ushort_t;
typedef unsigned int   uint_t;

// ---------------------------------------------------------------- helpers
__device__ __forceinline__ ushort_t f32_to_bf16(float f) {
    union { float f; unsigned int u; } v; v.f = f;
    unsigned int r = v.u + 0x7fffu + ((v.u >> 16) & 1u);   // RNE
    return (ushort_t)(r >> 16);
}

// pack two fp32 -> (bf16(hi)<<16)|bf16(lo) with +0x8000 round bias, 3 VALU ops
__device__ __forceinline__ uint_t pk_bf16(float lo, float hi) {
    uint_t ulo = __builtin_bit_cast(uint_t, lo) + 0x8000u;
    uint_t uhi = __builtin_bit_cast(uint_t, hi) + 0x8000u;
    return __builtin_amdgcn_perm(uhi, ulo, 0x07060302);  // bytes: lo[2],lo[3],hi[2],hi[3]
}

__device__ __forceinline__ void async_copy16(const ushort_t* g, ushort_t* l) {
    typedef const unsigned int __attribute__((address_space(1)))* gp_t;
    typedef       unsigned int __attribute__((address_space(3)))* lp_t;
    __builtin_amdgcn_global_load_lds((gp_t)(uintptr_t)g, (lp_t)(uintptr_t)l, 16, 0, 0);
}

// ---------------------------------------------------------------- fused fp32 -> bf16 cast
__global__ __launch_bounds__(256) void cast_all_kernel(
    const float* __restrict__ q, const float* __restrict__ k, const float* __restrict__ v,
    const float* __restrict__ wq, const float* __restrict__ wk,
    const float* __restrict__ wv, const float* __restrict__ wo,
    ushort_t* __restrict__ oq, ushort_t* __restrict__ ok, ushort_t* __restrict__ ov,
    ushort_t* __restrict__ owq, ushort_t* __restrict__ owk,
    ushort_t* __restrict__ owv, ushort_t* __restrict__ owo)
{
    const int NTD4 = (B_ * T_ * D_) / 4;   // 1048576
    const int NW4  = (D_ * D_) / 4;        // 262144
    int i = blockIdx.x * 256 + threadIdx.x;
    const float* s; ushort_t* d; int off;
    if (i < NTD4)              { s = q; d = oq; off = i; }
    else if (i < 2 * NTD4)     { s = k; d = ok; off = i - NTD4; }
    else if (i < 3 * NTD4)     { s = v; d = ov; off = i - 2 * NTD4; }
    else {
        int w = i - 3 * NTD4;
        int seg = w / NW4;  off = w - seg * NW4;
        s = (seg == 0) ? wq : (seg == 1) ? wk : (seg == 2) ? wv : wo;
        d = (seg == 0) ? owq : (seg == 1) ? owk : (seg == 2) ? owv : owo;
    }
    float4 x = ((const float4*)s)[off];
    ushort4 o;
    o.x = f32_to_bf16(x.x); o.y = f32_to_bf16(x.y);
    o.z = f32_to_bf16(x.z); o.w = f32_to_bf16(x.w);
    ((ushort4*)d)[off] = o;
}

// ---------------------------------------------------------------- R15: gemm_o rebuilt
// C = A(bf16[4096,1024]) * W^T + bias -> fp32 [4096,1024].
// 128x64 tile, BK=64, 256 threads (4 waves, 2m x 2n, per-wave 64x32 out).
// LDS: 2 bufs x (A 128x64 = 16KB + B 64x64 = 8KB) = 48KB -> 2 blocks/CU.
// STAGE-EARLY 2-phase (T3-minimum, m248: 92% of 8-phase): issue next tile's
// 6 copies BEFORE computing current tile; one __syncthreads per tile (its
// vmcnt(0)+lgkmcnt(0) drain is the publish point; copies had the whole
// ds_read+MFMA window to land). Old structure staged at the top of the SAME
// iteration it drained -> 32 full-latency stalls; now 16 partially-hidden.
// Swizzle (rule #21, same scheme as qkv8): LDS row r phys chunk p holds
// global chunk c = p ^ (r&7); staging uses pre-swizzled global source
// (linear LDS dest = wave base + lane*16 ✓); reads XOR the chunk index.
// MFMA k-order ascending (half0 then half1, tiles ascending) == old kernel's
// order -> bitwise-identical accumulation.
__global__ __launch_bounds__(256, 2) void gemm_o_kernel(
    const ushort_t* __restrict__ A, const ushort_t* __restrict__ W,
    const float* __restrict__ bias, float* __restrict__ out)
{
    __shared__ __align__(16) ushort_t sm[24576];   // 2 x 12288 shorts (48KB)
    const int tid  = threadIdx.x;
    const int lane = tid & 63;
    const int wv   = tid >> 6;        // 0..3
    const int wm   = (wv >> 1) * 64;  // 0, 64
    const int wn   = (wv & 1) * 32;   // 0, 32
    const int cl   = lane & 15;
    const int qd   = lane >> 4;
    const int swz  = cl & 7;
    const int coff = (qd ^ swz) * 8;  // k-half0 chunk byte-offset (shorts); half1 = ^32
    const int m0 = blockIdx.x * 128, n0 = blockIdx.y * 64;

    // staging map: thread -> rows r0 + {0,32,64,96} (A) / {0,32} (B),
    // phys chunk tid&7, pre-swizzled global chunk c0 = (tid&7) ^ (r0&7).
    // LDS dest offset = r0*64 + (tid&7)*8 = wave_base + lane*8 shorts (linear ✓)
    const int r0 = tid >> 3;              // 0..31
    const int c0 = (tid & 7) ^ (r0 & 7);
    const ushort_t* Ag = A + (size_t)(m0 + r0) * 1024 + c0 * 8;
    const ushort_t* Wg = W + (size_t)(n0 + r0) * 1024 + c0 * 8;
    const int ldst = r0 * 64 + (tid & 7) * 8;

    auto stage = [&](int t, int buf) {   // 6 copies: A rows r0+{0,32,64,96}, B rows r0+{0,32}
        const ushort_t* ga = Ag + t * 64;
        const ushort_t* gb = Wg + t * 64;
        ushort_t* la = sm + buf * 12288 + ldst;
        ushort_t* lb = sm + buf * 12288 + 8192 + ldst;
        async_copy16(ga,             la);
        async_copy16(ga + 32 * 1024, la + 32 * 64);
        async_copy16(ga + 64 * 1024, la + 64 * 64);
        async_copy16(ga + 96 * 1024, la + 96 * 64);
        async_copy16(gb,             lb);
        async_copy16(gb + 32 * 1024, lb + 32 * 64);
    };

    floatx4 acc[4][2];
    const floatx4 z4 = {0.f, 0.f, 0.f, 0.f};
    #pragma unroll
    for (int mi = 0; mi < 4; ++mi) { acc[mi][0] = z4; acc[mi][1] = z4; }

    stage(0, 0);
    __syncthreads();

    #pragma unroll 1
    for (int t = 0; t < 16; ++t) {
        const int cur = t & 1;
        if (t < 15) stage(t + 1, cur ^ 1);

        const ushort_t* Ab = sm + cur * 12288 + (wm + cl) * 64;
        const ushort_t* Bb = sm + cur * 12288 + 8192 + (wn + cl) * 64;
        short8 af[4][2], bf[2][2];
        #pragma unroll
        for (int mi = 0; mi < 4; ++mi) {
            af[mi][0] = *(const short8*)(Ab + mi * 1024 + coff);
            af[mi][1] = *(const short8*)(Ab + mi * 1024 + (coff ^ 32));
        }
        #pragma unroll
        for (int ni = 0; ni < 2; ++ni) {
            bf[ni][0] = *(const short8*)(Bb + ni * 1024 + coff);
            bf[ni][1] = *(const short8*)(Bb + ni * 1024 + (coff ^ 32));
        }
        #pragma unroll
        for (int mi = 0; mi < 4; ++mi)
            #pragma unroll
            for (int ni = 0; ni < 2; ++ni) {
                acc[mi][ni] = __builtin_amdgcn_mfma_f32_16x16x32_bf16(
                    af[mi][0], bf[ni][0], acc[mi][ni], 0, 0, 0);
                acc[mi][ni] = __builtin_amdgcn_mfma_f32_16x16x32_bf16(
                    af[mi][1], bf[ni][1], acc[mi][ni], 0, 0, 0);
            }
        __syncthreads();   // vmcnt(0)+lgkm(0)+barrier: publishes stage(t+1), frees buf cur
    }

    // epilogue: C/D col = lane&15 (n), row = qd*4 + r (m)
    #pragma unroll
    for (int mi = 0; mi < 4; ++mi) {
        #pragma unroll
        for (int ni = 0; ni < 2; ++ni) {
            const int n = n0 + wn + ni * 16 + cl;
            const float bn = bias[n];
            #pragma unroll
            for (int r = 0; r < 4; ++r) {
                const int m = m0 + wm + mi * 16 + qd * 4 + r;
                out[(size_t)m * D_ + n] = acc[mi][ni][r] + bn;
            }
        }
    }
}

// ---------------------------------------------------------------- R13: fused QKV GEMM, 256^2 8-phase
// (verified R5: passed, absmax 0.0078)
__device__ __forceinline__ void ldA4(short8 (&af)[4][2], const ushort_t* base, int coff) {
    #pragma unroll
    for (int mi = 0; mi < 4; ++mi) {
        af[mi][0] = *(const short8*)(base + mi * 1024 + coff);
        af[mi][1] = *(const short8*)(base + mi * 1024 + (coff ^ 32));
    }
}
__device__ __forceinline__ void ldB2(short8 (&bf)[2][2], const ushort_t* base, int coff) {
    #pragma unroll
    for (int ni = 0; ni < 2; ++ni) {
        bf[ni][0] = *(const short8*)(base + ni * 1024 + coff);
        bf[ni][1] = *(const short8*)(base + ni * 1024 + (coff ^ 32));
    }
}

template<int MQ, int NQ>
__device__ __forceinline__ void quad16(floatx4 (&acc)[8][4],
                                       const short8 (&af)[4][2],
                                       const short8 (&bf)[2][2])
{
    __builtin_amdgcn_s_setprio(1);
    #pragma unroll
    for (int mi = 0; mi < 4; ++mi)
        #pragma unroll
        for (int ni = 0; ni < 2; ++ni) {
            acc[MQ * 4 + mi][NQ * 2 + ni] = __builtin_amdgcn_mfma_f32_16x16x32_bf16(
                af[mi][0], bf[ni][0], acc[MQ * 4 + mi][NQ * 2 + ni], 0, 0, 0);
            acc[MQ * 4 + mi][NQ * 2 + ni] = __builtin_amdgcn_mfma_f32_16x16x32_bf16(
                af[mi][1], bf[ni][1], acc[MQ * 4 + mi][NQ * 2 + ni], 0, 0, 0);
        }
    __builtin_amdgcn_s_setprio(0);
}

__global__ void __launch_bounds__(512, 2) gemm_qkv8_kernel(
    const ushort_t* __restrict__ Xq, const ushort_t* __restrict__ Xk, const ushort_t* __restrict__ Xv,
    const ushort_t* __restrict__ Wqw, const ushort_t* __restrict__ Wkw, const ushort_t* __restrict__ Wvw,
    const float* __restrict__ bq, const float* __restrict__ bk, const float* __restrict__ bv,
    ushort_t* __restrict__ Qo, ushort_t* __restrict__ Ko, ushort_t* __restrict__ Vto)
{
    extern __shared__ __align__(16) ushort_t sm[];   // 131072 B

    const int bid    = blockIdx.x;
    const int gid    = (bid & 7) * 24 + (bid >> 3);
    const int m_tile = gid / 12;
    const int n_tile = gid - m_tile * 12;
    const int m0     = m_tile * 256;
    const int seg    = n_tile >> 2;          // 0:Q 1:K 2:V
    const int n0     = (n_tile & 3) * 256;   // within segment

    const ushort_t* A    = (seg == 0) ? Xq  : (seg == 1) ? Xk  : Xv;
    const ushort_t* W    = (seg == 0) ? Wqw : (seg == 1) ? Wkw : Wvw;
    const float*    bias = (seg == 0) ? bq  : (seg == 1) ? bk  : bv;

    const int tid  = threadIdx.x;
    const int lane = tid & 63;
    const int wv   = tid >> 6;        // 0..7
    const int wm   = wv >> 2;         // 0..1  (M half: 128 rows)
    const int wn   = wv & 3;          // 0..3  (64-col group)
    const int cl   = lane & 15;
    const int qd   = lane >> 4;
    const int swz  = cl & 7;
    const int coff = (qd ^ swz) * 8;  // chunk0 byte-offset (shorts); chunk1 = ^32

    const int r0 = tid >> 3;
    const int c0 = (tid & 7) ^ (r0 & 7);
    const ushort_t* gA = A + (size_t)(m0 + r0) * 1024 + c0 * 8;
    const ushort_t* gB = W + (size_t)(n0 + r0) * 1024 + c0 * 8;
    ushort_t* lbase = sm + tid * 8;

    auto stage = [&](int t, int op, int h) {
        if (t >= 16) return;
        const ushort_t* g = (op ? gB : gA) + (size_t)h * 131072 + (size_t)t * 64;
        ushort_t* l = lbase + (size_t)((t & 1) * 4 + op * 2 + h) * 8192;
        async_copy16(g, l);
        async_copy16(g + 65536, l + 4096);   // row r0+64
    };

    const ushort_t* A0 = sm + (0 * 4 + 0 * 2 + wm) * 8192 + cl * 64;
    const ushort_t* A1 = A0 + 4 * 8192;
    const ushort_t* B0 = sm + (0 * 4 + 1 * 2 + (wn >> 1)) * 8192 + (wn & 1) * 4096 + cl * 64;
    const ushort_t* B1 = B0 + 4 * 8192;

    floatx4 acc[8][4];
    const floatx4 z4 = {0.f, 0.f, 0.f, 0.f};
    #pragma unroll
    for (int i = 0; i < 8; ++i)
        #pragma unroll
        for (int j = 0; j < 4; ++j) acc[i][j] = z4;

    stage(0, 0, 0); stage(0, 0, 1); stage(0, 1, 0); stage(0, 1, 1);
    stage(1, 1, 0); stage(1, 1, 1);
    asm volatile("s_waitcnt vmcnt(4)" ::: "memory");
    __builtin_amdgcn_s_barrier();

    short8 af[4][2], bf0[2][2], bf1[2][2];

    #pragma unroll 1
    for (int it = 0; it < 7; ++it) {
        const int u = 2 * it, v = u + 1;
        // ---------------- tile u (dbuf 0) ----------------
        ldA4(af, A0, coff); ldB2(bf0, B0, coff);
        stage(v, 0, 0);
        __builtin_amdgcn_s_barrier();
        quad16<0, 0>(acc, af, bf0);
        __builtin_amdgcn_s_barrier();
        ldB2(bf1, B0 + 2048, coff);
        stage(v, 0, 1);
        __builtin_amdgcn_s_barrier();
        quad16<0, 1>(acc, af, bf1);
        __builtin_amdgcn_s_barrier();
        ldA4(af, A0 + 4096, coff);
        stage(u + 2, 1, 0);
        __builtin_amdgcn_s_barrier();
        quad16<1, 1>(acc, af, bf1);
        __builtin_amdgcn_s_barrier();
        stage(u + 2, 1, 1);
        asm volatile("s_waitcnt vmcnt(4)" ::: "memory");
        __builtin_amdgcn_s_barrier();
        quad16<1, 0>(acc, af, bf0);
        __builtin_amdgcn_s_barrier();
        // ---------------- tile v (dbuf 1) ----------------
        ldA4(af, A1, coff); ldB2(bf0, B1, coff);
        stage(u + 2, 0, 0);
        __builtin_amdgcn_s_barrier();
        quad16<0, 0>(acc, af, bf0);
        __builtin_amdgcn_s_barrier();
        ldB2(bf1, B1 + 2048, coff);
        stage(u + 2, 0, 1);
        __builtin_amdgcn_s_barrier();
        quad16<0, 1>(acc, af, bf1);
        __builtin_amdgcn_s_barrier();
        ldA4(af, A1 + 4096, coff);
        stage(v + 2, 1, 0);
        __builtin_amdgcn_s_barrier();
        quad16<1, 1>(acc, af, bf1);
        __builtin_amdgcn_s_barrier();
        stage(v + 2, 1, 1);
        asm volatile("s_waitcnt vmcnt(4)" ::: "memory");
        __builtin_amdgcn_s_barrier();
        quad16<1, 0>(acc, af, bf0);
        __builtin_amdgcn_s_barrier();
    }

    // peeled final iteration (tiles 14, 15): drains vmcnt(0) before tile 15
    ldA4(af, A0, coff); ldB2(bf0, B0, coff);
    stage(15, 0, 0);
    __builtin_amdgcn_s_barrier();
    quad16<0, 0>(acc, af, bf0);
    __builtin_amdgcn_s_barrier();
    ldB2(bf1, B0 + 2048, coff);
    stage(15, 0, 1);
    __builtin_amdgcn_s_barrier();
    quad16<0, 1>(acc, af, bf1);
    __builtin_amdgcn_s_barrier();
    ldA4(af, A0 + 4096, coff);
    __builtin_amdgcn_s_barrier();
    quad16<1, 1>(acc, af, bf1);
    __builtin_amdgcn_s_barrier();
    asm volatile("s_waitcnt vmcnt(0)" ::: "memory");
    __builtin_amdgcn_s_barrier();
    quad16<1, 0>(acc, af, bf0);
    __builtin_amdgcn_s_barrier();
    ldA4(af, A1, coff); ldB2(bf0, B1, coff);
    __builtin_amdgcn_s_barrier();
    quad16<0, 0>(acc, af, bf0);
    __builtin_amdgcn_s_barrier();
    ldB2(bf1, B1 + 2048, coff);
    __builtin_amdgcn_s_barrier();
    quad16<0, 1>(acc, af, bf1);
    __builtin_amdgcn_s_barrier();
    ldA4(af, A1 + 4096, coff);
    __builtin_amdgcn_s_barrier();
    quad16<1, 1>(acc, af, bf1);
    __builtin_amdgcn_s_barrier();
    quad16<1, 0>(acc, af, bf0);

    // ---------------- epilogue ----------------
    float bn[4];
    #pragma unroll
    for (int nf = 0; nf < 4; ++nf)
        bn[nf] = bias[n0 + wn * 64 + nf * 16 + cl];

    if (seg < 2) {
        ushort_t* out = (seg == 0) ? Qo : Ko;
        const float oscale = (seg == 0) ? KL2_ : 1.0f;
        #pragma unroll
        for (int mf = 0; mf < 8; ++mf) {
            #pragma unroll
            for (int nf = 0; nf < 4; ++nf) {
                const int n = n0 + wn * 64 + nf * 16 + cl;
                const int h = n >> 6, dk = n & 63;
                #pragma unroll
                for (int r = 0; r < 4; ++r) {
                    const int m = m0 + wm * 128 + mf * 16 + qd * 4 + r;
                    const int b = m >> 11, t = m & (T_ - 1);
                    out[(((size_t)(b * H_ + h)) * T_ + t) * DK_ + dk] =
                        f32_to_bf16((acc[mf][nf][r] + bn[nf]) * oscale);
                }
            }
        }
    } else {
        #pragma unroll
        for (int mf = 0; mf < 8; ++mf) {
            #pragma unroll
            for (int nf = 0; nf < 4; ++nf) {
                const int n = n0 + wn * 64 + nf * 16 + cl;
                const int h = n >> 6, dk = n & 63;
                const int mb = m0 + wm * 128 + mf * 16 + qd * 4;
                const int b = mb >> 11, t0 = mb & (T_ - 1);
                const int tsw = (t0 & ~60) | ((t0 & 48) >> 2) | ((t0 & 12) << 2);
                ushort4 o;
                o.x = f32_to_bf16(acc[mf][nf][0] + bn[nf]);
                o.y = f32_to_bf16(acc[mf][nf][1] + bn[nf]);
                o.z = f32_to_bf16(acc[mf][nf][2] + bn[nf]);
                o.w = f32_to_bf16(acc[mf][nf][3] + bn[nf]);
                *(ushort4*)(Vto + (((size_t)(b * H_ + h)) * DK_ + dk) * T_ + tsw) = o;
            }
        }
    }
}

// ---------------------------------------------------------------- flash attention
// (R5-verified version — 4 LDS buffers, two steps per barrier, pair-balanced;
// R14's counted-vmcnt variant measured neutral/-1.5us -> reverted)
__global__ __launch_bounds__(256, 2) void attn_kernel(
    const ushort_t* __restrict__ Q, const ushort_t* __restrict__ K,
    const ushort_t* __restrict__ Vs, ushort_t* __restrict__ O)
{
    __shared__ __align__(16) ushort_t sm[32768];  // 4 bufs x (K 4096 + V 4096)
    const int tid  = threadIdx.x;
    const int lane = tid & 63;
    const int wv   = tid >> 6;
    const int cl   = lane & 15;
    const int qd   = lane >> 4;
    const int swz  = cl & 7;
    const int h = blockIdx.x & (H_ - 1), b = blockIdx.x >> 4;
    const int p   = blockIdx.y;          // pair id 0..15
    const int btA = 31 - p;              // deep 64-row tile; tile B = p

    const ushort_t* Qh = Q  + ((size_t)(b * H_ + h) * T_) * DK_;
    const ushort_t* Kh = K  + ((size_t)(b * H_ + h) * T_) * DK_;
    const ushort_t* Vh = Vs + ((size_t)(b * H_ + h) * DK_) * T_;

    const int sr  = tid >> 3;
    const int sc  = tid & 7;
    const int scg = sc ^ (sr & 7);

    auto stage_step = [&](int s) {
        const int kbase = ((s <= btA) ? s : (s - btA - 1)) << 6;
        ushort_t* Kb = sm + (s & 3) * 8192;
        ushort_t* Vb = Kb + 4096;
        #pragma unroll
        for (int rr = 0; rr < 2; ++rr) {
            const int r = rr * 32 + sr;
            async_copy16(Kh + (size_t)(kbase + r) * DK_ + scg * 8, Kb + r * 64 + sc * 8);
            async_copy16(Vh + (size_t)r * T_ + kbase + scg * 8,    Vb + r * 64 + sc * 8);
        }
    };

    int qw = btA * 64 + wv * 16;         // wave's q-row base (current tile)
    short8 qf0 = *(const short8*)(Qh + (size_t)(qw + cl) * DK_ + qd * 8);
    short8 qf1 = *(const short8*)(Qh + (size_t)(qw + cl) * DK_ + 32 + qd * 8);

    stage_step(0);
    stage_step(1);

    const floatx4 z4 = {0.f, 0.f, 0.f, 0.f};
    floatx4 oaccT[4] = {z4, z4, z4, z4}; // O^T tiles: row = dk, col = q
    float l_ = 0.f;

    auto flush = [&](int q0w) {
        float l = l_;
        l += __shfl_xor(l, 16, 64);
        l += __shfl_xor(l, 32, 64);
        const float inv = 1.0f / l;
        ushort_t* Ob = O + ((size_t)(b * T_ + q0w + cl)) * D_ + h * DK_ + qd * 4;
        #pragma unroll
        for (int dt = 0; dt < 4; ++dt) {
            ushort4 o;
            o.x = f32_to_bf16(oaccT[dt][0] * inv);
            o.y = f32_to_bf16(oaccT[dt][1] * inv);
            o.z = f32_to_bf16(oaccT[dt][2] * inv);
            o.w = f32_to_bf16(oaccT[dt][3] * inv);
            *(ushort4*)(Ob + dt * 16) = o;
        }
    };

    auto compute_step = [&](int s) {
        const bool inA  = (s <= btA);
        const int kbase = (inA ? s : (s - btA - 1)) << 6;
        const bool diag = inA ? (s == btA) : (s == 32);
        ushort_t* cb = sm + (s & 3) * 8192;
        short8 kb[4][2];
        #pragma unroll
        for (int m = 0; m < 4; ++m)
            #pragma unroll
            for (int i = 0; i < 2; ++i)
                kb[m][i] = *(const short8*)(cb + (m * 16 + cl) * 64 + ((i * 4 + qd) ^ swz) * 8);
        floatx4 sacc[4] = {z4, z4, z4, z4};
        #pragma unroll
        for (int i = 0; i < 2; ++i)
            #pragma unroll
            for (int m = 0; m < 4; ++m)
                sacc[m] = __builtin_amdgcn_mfma_f32_16x16x32_bf16(
                    kb[m][i], (i ? qf1 : qf0), sacc[m], 0, 0, 0);
        const int qabs = qw + cl;
        float pr[4][4];
        if (diag) {
            #pragma unroll
            for (int c = 0; c < 4; ++c)
                #pragma unroll
                for (int r = 0; r < 4; ++r) {
                    const bool keep = (kbase + c * 16 + qd * 4 + r) <= qabs;
                    const float e = __builtin_amdgcn_exp2f(sacc[c][r]);
                    pr[c][r] = keep ? e : 0.f;
                    l_ += pr[c][r];
                }
        } else {
            #pragma unroll
            for (int c = 0; c < 4; ++c)
                #pragma unroll
                for (int r = 0; r < 4; ++r) {
                    pr[c][r] = __builtin_amdgcn_exp2f(sacc[c][r]);
                    l_ += pr[c][r];
                }
        }
        short8 va2[4][2];
        #pragma unroll
        for (int dt = 0; dt < 4; ++dt)
            #pragma unroll
            for (int h2 = 0; h2 < 2; ++h2)
                va2[dt][h2] = *(const short8*)(cb + 4096 + (dt * 16 + cl) * 64 +
                                               ((qd * 2 + h2) ^ swz) * 8);
        #pragma unroll
        for (int cp = 0; cp < 2; ++cp) {
            union { uint_t u[4]; short8 v; } pb;
            pb.u[0] = pk_bf16(pr[cp * 2][0],     pr[cp * 2][1]);
            pb.u[1] = pk_bf16(pr[cp * 2][2],     pr[cp * 2][3]);
            pb.u[2] = pk_bf16(pr[cp * 2 + 1][0], pr[cp * 2 + 1][1]);
            pb.u[3] = pk_bf16(pr[cp * 2 + 1][2], pr[cp * 2 + 1][3]);
            #pragma unroll
            for (int dt = 0; dt < 4; ++dt)
                oaccT[dt] = __builtin_amdgcn_mfma_f32_16x16x32_bf16(
                    va2[dt][cp], pb.v, oaccT[dt], 0, 0, 0);
        }
        if (s == btA) {
            flush(qw);
            #pragma unroll
            for (int dt = 0; dt < 4; ++dt) oaccT[dt] = z4;
            l_ = 0.f;
            qw = p * 64 + wv * 16;
            qf0 = *(const short8*)(Qh + (size_t)(qw + cl) * DK_ + qd * 8);
            qf1 = *(const short8*)(Qh + (size_t)(qw + cl) * DK_ + 32 + qd * 8);
        }
    };

    for (int g = 0; g < 17; ++g) {
        const int s0 = g * 2;
        __syncthreads();
        if (s0 + 2 <= 32) stage_step(s0 + 2);
        if (s0 + 3 <= 32) stage_step(s0 + 3);
        compute_step(s0);
        if (s0 + 1 <= 32) compute_step(s0 + 1);
    }
    flush(qw);                           // tile B
}

// ---------------------------------------------------------------- launch
extern "C" void kernel_launch(void* const* d_in, const int* in_sizes, int n_in,
                              void* d_out, int out_size, void* d_ws, size_t ws_size,
                              hipStream_t stream)
{
    const float* q_in = (const float*)d_in[0];
    const float* k_in = (const float*)d_in[1];
    const float* v_in = (const float*)d_in[2];
    const float* Wq   = (const float*)d_in[3];
    const float* bq   = (const float*)d_in[4];
    const float* Wk   = (const float*)d_in[5];
    const float* bk   = (const float*)d_in[6];
    const float* Wv   = (const float*)d_in[7];
    const float* bv   = (const float*)d_in[8];
    const float* Wo   = (const float*)d_in[9];
    const float* bo   = (const float*)d_in[10];
    float* out = (float*)d_out;

    const size_t NTD = (size_t)B_ * T_ * D_;  // 4,194,304
    const size_t NW  = (size_t)D_ * D_;       // 1,048,576
    ushort_t* ws  = (ushort_t*)d_ws;
    ushort_t* Xq  = ws;
    ushort_t* Xk  = Xq + NTD;
    ushort_t* Xv  = Xk + NTD;
    ushort_t* Wqb = Xv + NTD;
    ushort_t* Wkb = Wqb + NW;
    ushort_t* Wvb = Wkb + NW;
    ushort_t* Wob = Wvb + NW;
    ushort_t* Qd  = Wob + NW;
    ushort_t* Kd  = Qd + NTD;
    ushort_t* Vtd = Kd + NTD;
    ushort_t* Od  = Vtd + NTD;

    const int total4 = (int)((3 * NTD + 4 * NW) / 4);   // 4,194,304
    cast_all_kernel<<<dim3(total4 / 256), dim3(256), 0, stream>>>(
        q_in, k_in, v_in, Wq, Wk, Wv, Wo,
        Xq, Xk, Xv, Wqb, Wkb, Wvb, Wob);

    static bool s_attr = false;
    if (!s_attr) {
        (void)hipFuncSetAttribute((const void*)gemm_qkv8_kernel,
                                  hipFuncAttributeMaxDynamicSharedMemorySize, 131072);
        s_attr = true;
    }
    gemm_qkv8_kernel<<<dim3(192), dim3(512), 131072, stream>>>(
        Xq, Xk, Xv, Wqb, Wkb, Wvb, bq, bk, bv, Qd, Kd, Vtd);

    attn_kernel<<<dim3(32, 16), dim3(256), 0, stream>>>(Qd, Kd, Vtd, Od);

    gemm_o_kernel<<<dim3(32, 16), dim3(256), 0, stream>>>(Od, Wob, bo, out);
}